// Round 5
// baseline (13444.559 us; speedup 1.0000x reference)
//
#include <hip/hip_runtime.h>

// ---------------------------------------------------------------------------
// CNF forward: 2 blocks x Tsit5(10 steps x 6 stages).
// Round 5:
//  - jac_fused v2: 4 samples per block (weights staged once, masked 4x in
//    register), j in two 64-halves, 8 waves, MFMA-bound by construction.
//  - 2-phase software pipeline (stage next / compute cur / barrier) in both
//    jac and fwd, double-buffered LDS.
//  - fwd: 32x32 tiles -> 256 blocks (full CU coverage).
// ---------------------------------------------------------------------------

using short8 = __attribute__((ext_vector_type(8))) short;
using u16x8  = __attribute__((ext_vector_type(8))) unsigned short;
using f32x4v = __attribute__((ext_vector_type(4))) float;

__device__ __forceinline__ unsigned short f2bf(float f) {
  union { float f; unsigned u; } v; v.f = f;
  unsigned r = v.u + 0x7fffu + ((v.u >> 16) & 1u);
  return (unsigned short)(r >> 16);
}
__device__ __forceinline__ float bf2f(unsigned short h) {
  union { unsigned u; float f; } v; v.u = ((unsigned)h) << 16; return v.f;
}

typedef const __attribute__((address_space(1))) void gas_t;
typedef __attribute__((address_space(3))) void las_t;
__device__ __forceinline__ void gl_lds16(const void* g, void* l) {
  __builtin_amdgcn_global_load_lds((gas_t*)g, (las_t*)l, 16, 0, 0);
}

struct Coef5 { float v[5]; };
struct Coef6 { float v[6]; };

// ---------------------------------------------------------------------------
__global__ __launch_bounds__(256) void init_state(const float* __restrict__ y_in,
                                                  float* __restrict__ y,
                                                  float* __restrict__ lp) {
  int i = blockIdx.x * 256 + threadIdx.x;
  if (i < 512 * 128) y[i] = y_in[i];
  if (i < 512) lp[i] = 0.f;
}

// Weight prep (per ODE block):
//  w0y[j][a] = bf16(W0[1+j][a])   128x512   (jac GEMM-J B)
//  w0t[n][k] = split(W0[1+k][n])  512x128   (fwd L0 B)
//  w1t[b][a] = split(W1[a][b])    512x512   (fwd L1 B; hi = jac GEMM-J A)
//  w2t[c][b] = split(W2[b][c])    512x512   (fwd L2 B)
//  w3t[j][c] = split(W3[c][j])    128x512   (fwd L3 B; hi = jac GEMM-G B)
//  w2n[b][c] = bf16(W2[b][c])     512x512   (jac GEMM-G A)
__global__ __launch_bounds__(256) void cast_weights(
    const float* __restrict__ W0, const float* __restrict__ W1,
    const float* __restrict__ W2, const float* __restrict__ W3,
    unsigned short* __restrict__ w0y,
    unsigned short* __restrict__ w0tH, unsigned short* __restrict__ w0tL,
    unsigned short* __restrict__ w1tH, unsigned short* __restrict__ w1tL,
    unsigned short* __restrict__ w2tH, unsigned short* __restrict__ w2tL,
    unsigned short* __restrict__ w3tH, unsigned short* __restrict__ w3tL,
    unsigned short* __restrict__ w2n) {
  int i = blockIdx.x * 256 + threadIdx.x;
  if (i < 65536) {
    int j = i >> 9, a = i & 511;
    w0y[i] = f2bf(W0[(1 + j) * 512 + a]);
    return;
  }
  i -= 65536;
  if (i >= 2 * 65536 + 2 * 262144) {
    int q = i - (2 * 65536 + 2 * 262144);
    if (q < 262144) w2n[q] = f2bf(W2[q]);
    return;
  }
  float v;
  unsigned short* dh;
  unsigned short* dl;
  int di;
  if (i < 65536) {
    int n = i >> 7, k = i & 127;
    v = W0[(1 + k) * 512 + n]; dh = w0tH; dl = w0tL; di = i;
  } else if (i < 65536 + 262144) {
    int q = i - 65536; int n = q >> 9, k = q & 511;
    v = W1[k * 512 + n]; dh = w1tH; dl = w1tL; di = q;
  } else if (i < 65536 + 2 * 262144) {
    int q = i - 65536 - 262144; int c = q >> 9, b = q & 511;
    v = W2[b * 512 + c]; dh = w2tH; dl = w2tL; di = q;
  } else {
    int q = i - 65536 - 2 * 262144; int j = q >> 9, c = q & 511;
    v = W3[c * 128 + j]; dh = w3tH; dl = w3tL; di = q;
  }
  unsigned short hi = f2bf(v);
  dh[di] = hi;
  dl[di] = f2bf(v - bf2f(hi));
}

// yi = y + sum_{j<nc} ca[j]*ky[j], split into bf16 hi/lo.
__global__ __launch_bounds__(256) void prep_split(
    const float* __restrict__ y, const float* __restrict__ ky, Coef5 ca, int nc,
    unsigned short* __restrict__ yihi, unsigned short* __restrict__ yilo) {
  int i = (blockIdx.x * 256 + threadIdx.x) * 4;
  if (i >= 65536) return;
  float4 v = *(const float4*)&y[i];
  for (int j = 0; j < nc; ++j) {
    float4 u = *(const float4*)&ky[j * 65536 + i];
    v.x = fmaf(ca.v[j], u.x, v.x); v.y = fmaf(ca.v[j], u.y, v.y);
    v.z = fmaf(ca.v[j], u.z, v.z); v.w = fmaf(ca.v[j], u.w, v.w);
  }
  float a[4] = {v.x, v.y, v.z, v.w};
  ushort4 h4, l4;
  unsigned short* hp = (unsigned short*)&h4;
  unsigned short* lp4 = (unsigned short*)&l4;
#pragma unroll
  for (int e = 0; e < 4; ++e) {
    unsigned short h = f2bf(a[e]);
    hp[e] = h;
    lp4[e] = f2bf(a[e] - bf2f(h));
  }
  *(ushort4*)&yihi[i] = h4;
  *(ushort4*)&yilo[i] = l4;
}

// ---------------------------------------------------------------------------
// fwd split-bf16 MFMA GEMM: C[M,N] = act(A @ W + bias (+ t*wrow0)).
// Tile 32x32, BK=128, 4 waves 2x2, wave 16x16, 2-phase pipelined staging.
// ---------------------------------------------------------------------------
template <bool RELU>
__global__ __launch_bounds__(256, 2) void fwd_mfma(
    const unsigned short* __restrict__ Ahi, const unsigned short* __restrict__ Alo,
    const unsigned short* __restrict__ WtH, const unsigned short* __restrict__ WtL,
    const float* __restrict__ bias, const float* __restrict__ wrow0, float tval,
    float* __restrict__ Cf, unsigned short* __restrict__ Hhi,
    unsigned short* __restrict__ Hlo, int N, int K) {
  __shared__ unsigned short AsH[2][4096], AsL[2][4096], BsH[2][4096], BsL[2][4096];
  const int t = threadIdx.x, l = t & 63, w = t >> 6;
  const int wm = w >> 1, wn = w & 1, lr = l & 15, lg = l >> 4;
  const int m0 = blockIdx.y * 32, n0 = blockIdx.x * 32;
  const int lr7 = lr & 7;

  auto stage = [&](int cur, int k0) {
#pragma unroll
    for (int r = 0; r < 2; ++r) {
      int g = r * 256 + t;
      int row = g >> 4, gc = g & 15;
      size_t co = (size_t)k0 + ((gc ^ (row & 7)) << 3);
      size_t ao = (size_t)(m0 + row) * K + co;
      size_t bo = (size_t)(n0 + row) * K + co;
      int db = (r * 256 + (t & 192)) * 16;
      gl_lds16(Ahi + ao, (char*)AsH[cur] + db);
      gl_lds16(Alo + ao, (char*)AsL[cur] + db);
      gl_lds16(WtH + bo, (char*)BsH[cur] + db);
      gl_lds16(WtL + bo, (char*)BsL[cur] + db);
    }
  };

  f32x4v acc = {0.f, 0.f, 0.f, 0.f};
  stage(0, 0);
  __syncthreads();
  int cur = 0;
  for (int k0 = 0; k0 < K; k0 += 128) {
    if (k0 + 128 < K) stage(cur ^ 1, k0 + 128);
#pragma unroll
    for (int ks = 0; ks < 4; ++ks) {
      int sl = ((ks * 4 + lg) ^ lr7) << 4;
      int ab = (wm * 16 + lr) * 256 + sl;
      int bb = (wn * 16 + lr) * 256 + sl;
      short8 ah = *(const short8*)((const char*)AsH[cur] + ab);
      short8 al = *(const short8*)((const char*)AsL[cur] + ab);
      short8 bh = *(const short8*)((const char*)BsH[cur] + bb);
      short8 bl = *(const short8*)((const char*)BsL[cur] + bb);
      acc = __builtin_amdgcn_mfma_f32_16x16x32_bf16(ah, bh, acc, 0, 0, 0);
      acc = __builtin_amdgcn_mfma_f32_16x16x32_bf16(ah, bl, acc, 0, 0, 0);
      acc = __builtin_amdgcn_mfma_f32_16x16x32_bf16(al, bh, acc, 0, 0, 0);
    }
    __syncthreads();
    cur ^= 1;
  }

  int n = n0 + wn * 16 + lr;
  float be = bias[n];
  if (wrow0) be = fmaf(tval, wrow0[n], be);
#pragma unroll
  for (int r = 0; r < 4; ++r) {
    int m = m0 + wm * 16 + lg * 4 + r;
    float v = acc[r] + be;
    if (RELU) {
      v = fmaxf(v, 0.f);
      unsigned short h = f2bf(v);
      Hhi[m * N + n] = h;
      Hlo[m * N + n] = f2bf(v - bf2f(h));
    } else {
      Cf[m * N + n] = v;
    }
  }
}

// ---------------------------------------------------------------------------
// Fused Jacobian-trace kernel, 4 samples per block.
// Grid (cb=4, sg=128), 512 threads (8 waves, 2m x 4n), wave tile 64(b) x 16(j),
// j processed in two 64-halves. Per (jh): GEMM-J then GEMM-G, K=512, BK=64,
// 2-phase pipelined global_load_lds staging. Weights staged once per k0;
// per-sample K-mask applied in-register (AND with 0xFFFF/0 mask words).
//   J1[b][j] = sum_a w1t[b][a]*(D0[a]*w0y[j][a])
//   G [b][j] = sum_c w2n[b][c]*(D2[c]*w3t[j][c])
//   klp[cb][s] = sum_{b in chunk, j} D1[b]*J1[b][j]*G[b][j]
// ---------------------------------------------------------------------------
__device__ __forceinline__ void jac_phase(
    f32x4v (&acc)[4][4], const unsigned short* __restrict__ Abase,
    const unsigned short* __restrict__ Bbase, const unsigned short* Mk,
    unsigned short (*As)[8192], unsigned short (*Bs)[4096],
    int t, int wm, int wn, int lr, int lg) {
  const int lr7 = lr & 7;
  auto stage = [&](int cur, int k0) {
#pragma unroll
    for (int r = 0; r < 2; ++r) {
      int g = r * 512 + t;
      int row = g >> 3, gc = g & 7;
      gl_lds16(Abase + (size_t)row * 512 + k0 + ((gc ^ (row & 7)) << 3),
               (char*)As[cur] + (r * 512 + (t & 448)) * 16);
    }
    {
      int row = t >> 3, gc = t & 7;
      gl_lds16(Bbase + (size_t)row * 512 + k0 + ((gc ^ (row & 7)) << 3),
               (char*)Bs[cur] + (t & 448) * 16);
    }
  };
  stage(0, 0);
  __syncthreads();
  int cur = 0;
  for (int k0 = 0; k0 < 512; k0 += 64) {
    if (k0 + 64 < 512) stage(cur ^ 1, k0 + 64);
#pragma unroll
    for (int ks = 0; ks < 2; ++ks) {
      const int sl = ((ks * 4 + lg) ^ lr7) << 4;
      short8 af[4];
#pragma unroll
      for (int fm = 0; fm < 4; ++fm)
        af[fm] = *(const short8*)((const char*)As[cur] +
                                  (wm * 64 + fm * 16 + lr) * 128 + sl);
      u16x8 bv = *(const u16x8*)((const char*)Bs[cur] + (wn * 16 + lr) * 128 + sl);
#pragma unroll
      for (int s = 0; s < 4; ++s) {
        u16x8 mk = *(const u16x8*)&Mk[s * 512 + k0 + ks * 32 + lg * 8];
        short8 bm = (short8)(bv & mk);
#pragma unroll
        for (int fm = 0; fm < 4; ++fm)
          acc[s][fm] = __builtin_amdgcn_mfma_f32_16x16x32_bf16(af[fm], bm,
                                                               acc[s][fm], 0, 0, 0);
      }
    }
    __syncthreads();
    cur ^= 1;
  }
}

__global__ __launch_bounds__(512, 2) void jac_fused(
    const unsigned short* __restrict__ w1t, const unsigned short* __restrict__ w0y,
    const unsigned short* __restrict__ w2n, const unsigned short* __restrict__ w3t,
    const unsigned short* __restrict__ d0m, const unsigned short* __restrict__ d1m,
    const unsigned short* __restrict__ d2m, float* __restrict__ klp) {
  __shared__ unsigned short As[2][8192];   // 128x64 x2 = 32 KB
  __shared__ unsigned short Bs[2][4096];   //  64x64 x2 = 16 KB
  __shared__ unsigned short Ms0[2048], Ms1[2048], Ms2[2048];  // 4 samples x 512
  __shared__ float red[32];
  const int cb = blockIdx.x, s0 = blockIdx.y * 4;
  const int t = threadIdx.x, l = t & 63, w = t >> 6;
  const int wm = w >> 2, wn = w & 3;
  const int lr = l & 15, lg = l >> 4;

  if (t < 256) {
    gl_lds16(d0m + (size_t)s0 * 512 + t * 8, (char*)Ms0 + (t & 192) * 16);
    gl_lds16(d2m + (size_t)s0 * 512 + t * 8, (char*)Ms2 + (t & 192) * 16);
  } else {
    int t2 = t - 256;
    gl_lds16(d1m + (size_t)s0 * 512 + t2 * 8, (char*)Ms1 + (t2 & 192) * 16);
  }
  __syncthreads();
  {
    unsigned* M0 = (unsigned*)Ms0;
    unsigned* M2 = (unsigned*)Ms2;
#pragma unroll
    for (int q = 0; q < 2; ++q) {
      int idx = q * 512 + t;
      unsigned v0 = M0[idx], v2 = M2[idx];
      M0[idx] = ((v0 & 0xFFFFu) ? 0xFFFFu : 0u) | ((v0 >> 16) ? 0xFFFF0000u : 0u);
      M2[idx] = ((v2 & 0xFFFFu) ? 0xFFFFu : 0u) | ((v2 >> 16) ? 0xFFFF0000u : 0u);
    }
  }
  __syncthreads();

  float part[4] = {0.f, 0.f, 0.f, 0.f};
#pragma unroll 1
  for (int jh = 0; jh < 2; ++jh) {
    f32x4v accJ[4][4], accG[4][4];
#pragma unroll
    for (int s = 0; s < 4; ++s)
#pragma unroll
      for (int fm = 0; fm < 4; ++fm) {
        accJ[s][fm] = f32x4v{0.f, 0.f, 0.f, 0.f};
        accG[s][fm] = f32x4v{0.f, 0.f, 0.f, 0.f};
      }
    jac_phase(accJ, w1t + (size_t)cb * 65536, w0y + (size_t)jh * 32768, Ms0,
              As, Bs, t, wm, wn, lr, lg);
    jac_phase(accG, w2n + (size_t)cb * 65536, w3t + (size_t)jh * 32768, Ms2,
              As, Bs, t, wm, wn, lr, lg);
#pragma unroll
    for (int s = 0; s < 4; ++s) {
#pragma unroll
      for (int fm = 0; fm < 4; ++fm) {
        int bb = cb * 128 + wm * 64 + fm * 16 + lg * 4;
        ushort4 m1 = *(const ushort4*)&Ms1[s * 512 + bb];
        unsigned short mm[4] = {m1.x, m1.y, m1.z, m1.w};
#pragma unroll
        for (int r = 0; r < 4; ++r)
          part[s] += (mm[r] ? accJ[s][fm][r] * accG[s][fm][r] : 0.f);
      }
    }
  }
#pragma unroll
  for (int s = 0; s < 4; ++s) {
#pragma unroll
    for (int off = 1; off < 64; off <<= 1) part[s] += __shfl_xor(part[s], off);
  }
  if (l == 0) {
#pragma unroll
    for (int s = 0; s < 4; ++s) red[w * 4 + s] = part[s];
  }
  __syncthreads();
  if (t < 4) {
    float tot = 0.f;
#pragma unroll
    for (int w2 = 0; w2 < 8; ++w2) tot += red[w2 * 4 + t];
    klp[cb * 512 + s0 + t] = tot;
  }
}

// y += sum_i db[i]*ky[i];  lp += sum_i db[i]*(sum_{4 chunks} klp[i][cb][s])
__global__ __launch_bounds__(256) void step_update(float* __restrict__ y,
                                                   float* __restrict__ lp,
                                                   const float* __restrict__ ky,
                                                   const float* __restrict__ klp_part,
                                                   Coef6 db) {
  int i = blockIdx.x * 256 + threadIdx.x;
  if (i < 65536) {
    float a = y[i];
#pragma unroll
    for (int j = 0; j < 6; ++j) a += db.v[j] * ky[j * 65536 + i];
    y[i] = a;
  }
  if (i < 512) {
    float l = lp[i];
#pragma unroll
    for (int j = 0; j < 6; ++j) {
      const float* kp = klp_part + j * 2048;
      float tr = kp[i] + kp[512 + i] + kp[1024 + i] + kp[1536 + i];
      l += db.v[j] * tr;
    }
    lp[i] = l;
  }
}

__global__ __launch_bounds__(64) void finalize(const float* __restrict__ y,
                                               const float* __restrict__ lp,
                                               float* __restrict__ out) {
  int s = blockIdx.x, l = threadIdx.x;
  float v0 = y[s * 128 + l], v1 = y[s * 128 + 64 + l];
  float sum = v0 * v0 + v1 * v1;
#pragma unroll
  for (int off = 32; off; off >>= 1) sum += __shfl_down(sum, off);
  if (l == 0) out[s] = lp[s] + (-0.5f) * (1.8378770664093453f + sum);
}

// ---------------------------------------------------------------------------
extern "C" void kernel_launch(void* const* d_in, const int* in_sizes, int n_in,
                              void* d_out, int out_size, void* d_ws, size_t ws_size,
                              hipStream_t stream) {
  const float* y_in = (const float*)d_in[0];
  const float* Ws0 = (const float*)d_in[1];
  const float* bs0 = (const float*)d_in[2];
  const float* Ws1 = (const float*)d_in[3];
  const float* bs1 = (const float*)d_in[4];
  const float* Ws2 = (const float*)d_in[5];
  const float* bs2 = (const float*)d_in[6];
  const float* Ws3 = (const float*)d_in[7];
  const float* bs3 = (const float*)d_in[8];
  float* out = (float*)d_out;

  char* ws = (char*)d_ws;
  size_t off = 0;
  auto alloc = [&](size_t bytes) {
    void* p = ws + off;
    off = (off + bytes + 255) & ~(size_t)255;
    return p;
  };
  float* y  = (float*)alloc(65536 * 4);
  float* lp = (float*)alloc(512 * 4);
  unsigned short* yihi = (unsigned short*)alloc(65536 * 2);
  unsigned short* yilo = (unsigned short*)alloc(65536 * 2);
  unsigned short* h0hi = (unsigned short*)alloc(262144 * 2);
  unsigned short* h0lo = (unsigned short*)alloc(262144 * 2);
  unsigned short* h1hi = (unsigned short*)alloc(262144 * 2);
  unsigned short* h1lo = (unsigned short*)alloc(262144 * 2);
  unsigned short* h2hi = (unsigned short*)alloc(262144 * 2);
  unsigned short* h2lo = (unsigned short*)alloc(262144 * 2);
  float* ky  = (float*)alloc(6 * 65536 * 4);
  float* klp = (float*)alloc(6 * 2048 * 4);
  unsigned short* w0y  = (unsigned short*)alloc(65536 * 2);
  unsigned short* w0tH = (unsigned short*)alloc(65536 * 2);
  unsigned short* w0tL = (unsigned short*)alloc(65536 * 2);
  unsigned short* w1tH = (unsigned short*)alloc(262144 * 2);
  unsigned short* w1tL = (unsigned short*)alloc(262144 * 2);
  unsigned short* w2tH = (unsigned short*)alloc(262144 * 2);
  unsigned short* w2tL = (unsigned short*)alloc(262144 * 2);
  unsigned short* w3tH = (unsigned short*)alloc(65536 * 2);
  unsigned short* w3tL = (unsigned short*)alloc(65536 * 2);
  unsigned short* w2n  = (unsigned short*)alloc(262144 * 2);
  (void)ws_size; (void)in_sizes; (void)n_in; (void)out_size;

  static const double DT = -0.1;
  static const double TC[6] = {0.0, 0.161, 0.327, 0.9, 0.9800255409045097, 1.0};
  static const double TA[6][5] = {
      {0, 0, 0, 0, 0},
      {0.161, 0, 0, 0, 0},
      {-0.008480655492356989, 0.335480655492357, 0, 0, 0},
      {2.8971530571054935, -6.359448489975075, 4.3622954328695815, 0, 0},
      {5.325864828439257, -11.748883564062828, 7.4955393428898365, -0.09249506636175525, 0},
      {5.86145544294642, -12.92096931784711, 8.159367898576159, -0.071584973281401,
       -0.028269050394068383}};
  static const double TB[6] = {0.09646076681806523, 0.01, 0.4798896504144996,
                               1.379008574103742, -3.290069515436081, 2.324710524099774};

  init_state<<<dim3(256), dim3(256), 0, stream>>>(y_in, y, lp);

  for (int blk = 0; blk < 2; ++blk) {
    const float* W0 = Ws0 + blk * 129 * 512;
    const float* b0 = bs0 + blk * 512;
    const float* W1 = Ws1 + blk * 262144;
    const float* b1 = bs1 + blk * 512;
    const float* W2 = Ws2 + blk * 262144;
    const float* b2 = bs2 + blk * 512;
    const float* W3 = Ws3 + blk * 65536;
    const float* b3 = bs3 + blk * 128;

    cast_weights<<<dim3(3840), dim3(256), 0, stream>>>(
        W0, W1, W2, W3, w0y, w0tH, w0tL, w1tH, w1tL, w2tH, w2tL, w3tH, w3tL, w2n);

    for (int n = 0; n < 10; ++n) {
      float t = 1.0f + (-0.1f) * (float)n;
      for (int i = 0; i < 6; ++i) {
        float ti = t + (float)(TC[i] * DT);
        Coef5 ca;
        for (int j = 0; j < 5; ++j) ca.v[j] = (j < i) ? (float)(DT * TA[i][j]) : 0.f;

        prep_split<<<dim3(64), dim3(256), 0, stream>>>(y, ky, ca, i, yihi, yilo);
        fwd_mfma<true><<<dim3(16, 16), 256, 0, stream>>>(
            yihi, yilo, w0tH, w0tL, b0, W0, ti, nullptr, h0hi, h0lo, 512, 128);
        fwd_mfma<true><<<dim3(16, 16), 256, 0, stream>>>(
            h0hi, h0lo, w1tH, w1tL, b1, nullptr, 0.f, nullptr, h1hi, h1lo, 512, 512);
        fwd_mfma<true><<<dim3(16, 16), 256, 0, stream>>>(
            h1hi, h1lo, w2tH, w2tL, b2, nullptr, 0.f, nullptr, h2hi, h2lo, 512, 512);
        fwd_mfma<false><<<dim3(4, 16), 256, 0, stream>>>(
            h2hi, h2lo, w3tH, w3tL, b3, nullptr, 0.f, ky + i * 65536, nullptr,
            nullptr, 128, 512);
        jac_fused<<<dim3(4, 128), 512, 0, stream>>>(
            w1tH, w0y, w2n, w3tH, h0hi, h1hi, h2hi, klp + i * 2048);
      }
      Coef6 db;
      for (int i2 = 0; i2 < 6; ++i2) db.v[i2] = (float)(DT * TB[i2]);
      step_update<<<dim3(256), dim3(256), 0, stream>>>(y, lp, ky, klp, db);
    }
  }
  finalize<<<dim3(512), dim3(64), 0, stream>>>(y, lp, out);
}